// Round 7
// baseline (469.673 us; speedup 1.0000x reference)
//
#include <hip/hip_runtime.h>
#include <hip/hip_bf16.h>

typedef unsigned short u16;
typedef unsigned int u32;
typedef __attribute__((ext_vector_type(8))) short s16x8;
typedef __attribute__((ext_vector_type(4))) float f32x4;

__device__ __forceinline__ float bf2f(u16 v) {
    union { u32 u; float f; } x; x.u = ((u32)v) << 16; return x.f;
}
__device__ __forceinline__ u16 f2bf(float f) {
    union { float f; u32 u; } x; x.f = f;
    u32 r = x.u + 0x7fffu + ((x.u >> 16) & 1u);
    return (u16)(r >> 16);
}
// pack two f32 -> bf16x2 (low = a, high = b)
__device__ __forceinline__ u32 f2bf_pk(float a, float b) {
    __hip_bfloat162 hb = __float22bfloat162_rn(make_float2(a, b));
    union { __hip_bfloat162 h; u32 u; } c; c.h = hb; return c.u;
}
// async global->LDS, 16B per lane. LDS dest must be wave-uniform base + lane*16
__device__ __forceinline__ void gl2lds(const u16* g, u16* l) {
    __builtin_amdgcn_global_load_lds(
        (const __attribute__((address_space(1))) unsigned int*)g,
        (__attribute__((address_space(3))) unsigned int*)l, 16, 0, 0);
}

#define L_TOK 21952      // 28^3
#define C_DIM 192
#define LOG2E 1.4426950408889634f
#define Q2SCALE 0.2550565444463649f   // (1/sqrt(32)) * log2(e)

// ---------------------------------------------------------------------------
// Convert the 4 weight matrices f32 -> bf16 (contiguous dst buffer).
// ---------------------------------------------------------------------------
__global__ __launch_bounds__(256) void cvt_k(const float* __restrict__ s0, // 110592 qkv_w
                                             const float* __restrict__ s1, // 36864  proj_w
                                             const float* __restrict__ s2, // 147456 fc1_w
                                             const float* __restrict__ s3, // 147456 fc2_w
                                             u16* __restrict__ dst)
{
    int i = blockIdx.x * 256 + threadIdx.x;   // grid covers 442368
    float v;
    if (i < 110592) v = s0[i];
    else if (i < 147456) v = s1[i - 110592];
    else if (i < 294912) v = s2[i - 147456];
    else v = s3[i - 294912];
    dst[i] = f2bf(v);
}

// ---------------------------------------------------------------------------
// Precompute rel-pos bias per head, premultiplied by log2(e):
// bias6[hh][n][m] (bf16), 6*343*343 = 1.4 MB -> L2/L3 resident.
// ---------------------------------------------------------------------------
__global__ __launch_bounds__(256) void bias6_k(const float* __restrict__ rpb,
                                               u16* __restrict__ bias6)
{
    const int m = blockIdx.x * 256 + threadIdx.x;
    if (m >= 343) return;
    const int n = blockIdx.y, hh = blockIdx.z;
    int hq = n / 49, r1 = n - hq * 49, wq = r1 / 7, tq = r1 - wq * 7;
    int hm = m / 49, r2 = m - hm * 49, wm = r2 / 7, tm = r2 - wm * 7;
    int idx = ((hq - hm + 6) * 13 + (wq - wm + 6)) * 13 + (tq - tm + 6);
    bias6[((size_t)hh * 343 + n) * 343 + m] = f2bf(rpb[idx * 6 + hh] * LOG2E);
}

// ---------------------------------------------------------------------------
// LayerNorm: f32 in, bf16 out. MODE 0: LN + cyclic shift(-3) + window
// partition scatter -> xw (Bn*343, 192).  MODE 1: LN, same-row out.
// ---------------------------------------------------------------------------
template<int MODE>
__global__ __launch_bounds__(256) void ln_k(const float* __restrict__ in,
                                            const float* __restrict__ g,
                                            const float* __restrict__ b,
                                            u16* __restrict__ out)
{
    const int lane = threadIdx.x & 63, wv = threadIdx.x >> 6;
    const int tok = blockIdx.x * 4 + wv;   // < 43904 always (10976*4)
    size_t base = (size_t)tok * C_DIM;
    float x0 = in[base + lane];
    float x1 = in[base + 64 + lane];
    float x2 = in[base + 128 + lane];
    float s = x0 + x1 + x2;
    float sq = x0 * x0 + x1 * x1 + x2 * x2;
    #pragma unroll
    for (int off = 32; off > 0; off >>= 1) {
        s += __shfl_xor(s, off, 64);
        sq += __shfl_xor(sq, off, 64);
    }
    const float mean = s * (1.0f / 192.0f);
    float var = sq * (1.0f / 192.0f) - mean * mean;
    var = fmaxf(var, 0.0f);
    const float rstd = rsqrtf(var + 1e-5f);

    size_t obase;
    if (MODE == 0) {
        int bi = tok / L_TOK;
        int l = tok - bi * L_TOK;
        int h = l / 784;
        int rm = l - h * 784;
        int w = rm / 28;
        int t = rm - w * 28;
        int hs = h + 25; if (hs >= 28) hs -= 28;
        int ws = w + 25; if (ws >= 28) ws -= 28;
        int ts = t + 25; if (ts >= 28) ts -= 28;
        int win = ((bi * 4 + hs / 7) * 4 + ws / 7) * 4 + ts / 7;
        int n = (hs % 7) * 49 + (ws % 7) * 7 + (ts % 7);
        obase = ((size_t)win * 343 + n) * C_DIM;
    } else {
        obase = base;
    }
    #pragma unroll
    for (int i = 0; i < 3; i++) {
        int c = lane + i * 64;
        float xv = (i == 0) ? x0 : (i == 1) ? x1 : x2;
        float y = (xv - mean) * rstd * g[c] + b[c];
        out[obase + c] = f2bf(y);
    }
}

// ---------------------------------------------------------------------------
// bf16 MFMA GEMM: C(M,N) = A(M,K) @ W(N,K)^T + bias(f32). 128x64 tile, BK=32.
// Staging via global_load_lds width-16 (LDS dest = 16*t bytes = wave-uniform
// base + lane*16). Grid is (N/64, 343): n0 = fast dim so blocks sharing a
// row-tile dispatch together -> A re-reads hit L2/L3.
// EPI: 0 = bias, q-cols (gcol<192) pre-scaled by scale*log2e -> bf16 (QKV)
//      1 = bias + exact GELU -> bf16 (fc1)
//      2 = bias + f32 residual -> f32 out (fc2 -> d_out)
//      3 = bias + window-reverse/unshift scatter + f32 residual -> f32 (proj)
// ---------------------------------------------------------------------------
template<int K, int EPI>
__global__ __launch_bounds__(256) void gemm_k(const u16* __restrict__ A,
                                              const u16* __restrict__ W,
                                              const float* __restrict__ bias,
                                              void* __restrict__ outp,
                                              const void* __restrict__ resp,
                                              int Ncols)
{
    __shared__ __align__(16) u16 As[128 * 32];
    __shared__ __align__(16) u16 Bs[64 * 32];
    const int t = threadIdx.x;
    const int bm = blockIdx.y;
    const int n0 = blockIdx.x * 64;
    const int lane = t & 63, wv = t >> 6;
    const int wm = (wv >> 1) * 64, wn = (wv & 1) * 32;
    const int r16 = lane & 15, quad = lane >> 4;

    f32x4 acc[4][2];
    #pragma unroll
    for (int i = 0; i < 4; i++)
        #pragma unroll
        for (int j = 0; j < 2; j++) acc[i][j] = (f32x4){0.f, 0.f, 0.f, 0.f};

    const int ar = t >> 2, ac = (t & 3) * 8;
    const size_t abase = (size_t)bm * 128 * K;

    for (int k0 = 0; k0 < K; k0 += 32) {
        gl2lds(&A[abase + (size_t)ar * K + k0 + ac], &As[8 * t]);
        gl2lds(&A[abase + (size_t)(ar + 64) * K + k0 + ac], &As[2048 + 8 * t]);
        gl2lds(&W[(size_t)(n0 + ar) * K + k0 + ac], &Bs[8 * t]);
        __syncthreads();
        s16x8 af[4], bf[2];
        #pragma unroll
        for (int fm = 0; fm < 4; fm++)
            af[fm] = *(const s16x8*)&As[(wm + fm * 16 + r16) * 32 + quad * 8];
        #pragma unroll
        for (int fn = 0; fn < 2; fn++)
            bf[fn] = *(const s16x8*)&Bs[(wn + fn * 16 + r16) * 32 + quad * 8];
        #pragma unroll
        for (int fm = 0; fm < 4; fm++)
            #pragma unroll
            for (int fn = 0; fn < 2; fn++)
                acc[fm][fn] = __builtin_amdgcn_mfma_f32_16x16x32_bf16(af[fm], bf[fn], acc[fm][fn], 0, 0, 0);
        __syncthreads();
    }

    #pragma unroll
    for (int fm = 0; fm < 4; fm++) {
        #pragma unroll
        for (int fn = 0; fn < 2; fn++) {
            #pragma unroll
            for (int r = 0; r < 4; r++) {
                const int grow = bm * 128 + wm + fm * 16 + quad * 4 + r;
                const int gcol = n0 + wn + fn * 16 + r16;
                float v = acc[fm][fn][r] + bias[gcol];
                if (EPI == 0) {
                    if (gcol < 192) v *= Q2SCALE;   // pre-scale q (incl. log2e)
                    ((u16*)outp)[(size_t)grow * Ncols + gcol] = f2bf(v);
                } else if (EPI == 1) {
                    v = 0.5f * v * (1.0f + erff(v * 0.70710678118654752f));
                    ((u16*)outp)[(size_t)grow * Ncols + gcol] = f2bf(v);
                } else if (EPI == 2) {
                    size_t o = (size_t)grow * C_DIM + gcol;
                    ((float*)outp)[o] = v + ((const float*)resp)[o];
                } else { // EPI == 3: proj scatter + residual(x f32) -> x2 f32
                    int win = grow / 343, n = grow - win * 343;
                    int bi = win >> 6, wi = win & 63;
                    int hw = wi >> 4, ww = (wi >> 2) & 3, tw = wi & 3;
                    int ph = n / 49, rem = n - ph * 49;
                    int pw = rem / 7, pt = rem - pw * 7;
                    int h = hw * 7 + ph + 3; if (h >= 28) h -= 28;
                    int w = ww * 7 + pw + 3; if (w >= 28) w -= 28;
                    int tt = tw * 7 + pt + 3; if (tt >= 28) tt -= 28;
                    int l = (h * 28 + w) * 28 + tt;
                    size_t o = ((size_t)bi * L_TOK + l) * C_DIM + gcol;
                    ((float*)outp)[o] = v + ((const float*)resp)[o];
                }
            }
        }
    }
}

// ---------------------------------------------------------------------------
// MFMA attention. Block = (head hh, window win), 8 waves (512 thr).
// q pre-scaled by scale*log2e; bias premultiplied by log2e -> p = exp2(s).
// Structural mask (no memory): region id per axis r = 0 if wc<3 else
// (pos<4?1:2); equal-region -> attend, else p = 0.
// P round-trip: packed bf16x2 ds_write_b32; Vt columns pre-permuted so the
// packed physical order is the PV contraction order (pure index relabel):
//   phys p = 2*(l&15) + (l>>4)  within each 32-col chunk.
// LDS: Ks 352x40 + Vt 32x360 + Pb 8x16x40 + Cn 344 = 62128 B (2 blocks/CU).
// ---------------------------------------------------------------------------
__global__ __launch_bounds__(512, 4) void attn_k(const u16* __restrict__ qkv,
                                                 const u16* __restrict__ bias6,
                                                 u16* __restrict__ out)
{
    __shared__ __align__(16) u16 Ks[352 * 40];
    __shared__ __align__(16) u16 Vt[32 * 360];
    __shared__ __align__(16) u16 Pb[8][16 * 40];
    __shared__ u16 Cn[344];

    const int hh = blockIdx.x;   // head 0..5
    const int win = blockIdx.y;  // 0..127
    const int wi = win & 63;
    const int t = threadIdx.x, lane = t & 63, wv = t >> 6;
    const int r16 = lane & 15, quad = lane >> 4;
    const size_t qbase = (size_t)win * 343 * 576 + hh * 32;

    // ---- stage K rows (343 x 32), zero pad rows 343..351 ----
    for (int j = t; j < 343 * 4; j += 512) {
        int m = j >> 2, ch = j & 3;
        *(uint4*)&Ks[m * 40 + ch * 8] = *(const uint4*)&qkv[qbase + (size_t)m * 576 + 192 + ch * 8];
    }
    if (t < 36) {
        int m = 343 + (t >> 2), ch = t & 3;
        *(uint4*)&Ks[m * 40 + ch * 8] = (uint4){0u, 0u, 0u, 0u};
    }
    // ---- stage V transposed + column-permuted: Vt[d][phys(m)] ----
    for (int i = t; i < 343 * 16; i += 512) {
        int m = i >> 4, d2 = (i & 15) * 2;
        int pm = (m & ~31) + 2 * (m & 15) + ((m >> 4) & 1);
        u32 w2 = *(const u32*)&qkv[qbase + (size_t)m * 576 + 384 + d2];
        Vt[d2 * 360 + pm] = (u16)(w2 & 0xffffu);
        Vt[(d2 + 1) * 360 + pm] = (u16)(w2 >> 16);
    }
    // zero pads (logical m 343..351 at their permuted slots), all 32 d rows
    for (int i = t; i < 32 * 9; i += 512) {
        int d = i / 9, m = 343 + i % 9;
        int pm = (m & ~31) + 2 * (m & 15) + ((m >> 4) & 1);
        Vt[d * 360 + pm] = 0;
    }
    // ---- structural mask: region-count table for this window ----
    {
        const int hw = (wi >> 4) & 3, ww = (wi >> 2) & 3, tw = wi & 3;
        for (int n = t; n < 344; n += 512) {
            int nn = n > 342 ? 342 : n;
            int ph = nn / 49, rem = nn - ph * 49;
            int pw = rem / 7, pt = rem - pw * 7;
            int rh = (hw == 3) ? (ph < 4 ? 1 : 2) : 0;
            int rw = (ww == 3) ? (pw < 4 ? 1 : 2) : 0;
            int rt = (tw == 3) ? (pt < 4 ? 1 : 2) : 0;
            Cn[n] = (u16)(rh * 9 + rw * 3 + rt);
        }
    }
    __syncthreads();

    const u16* biash = bias6 + (size_t)hh * 343 * 343;

    // per-lane column region ids (cols fixed across Q-tiles)
    u16 cntc[22];
    #pragma unroll
    for (int fn = 0; fn < 22; fn++) {
        int col = fn * 16 + r16; if (col > 342) col = 342;
        cntc[fn] = Cn[col];
    }

    for (int qt = 0; qt < 3; qt++) {
        const int row0 = qt * 128 + wv * 16;         // wave's 16 rows
        if (row0 > 342) continue;                    // wave-uniform early out
        // ---- Q A-fragment (row = r16, k = quad*8+j), clamped rows ----
        int qrow = row0 + r16; if (qrow > 342) qrow = 342;
        s16x8 qa = *(const s16x8*)&qkv[qbase + (size_t)qrow * 576 + quad * 8];

        // row region ids for this tile
        u16 cr[4];
        #pragma unroll
        for (int r = 0; r < 4; r++) {
            int n = row0 + quad * 4 + r; if (n > 342) n = 342;
            cr[r] = Cn[n];
        }

        // ---- S = Q K^T with bias-initialized accumulators ----
        f32x4 sacc[22];
        #pragma unroll
        for (int fn = 0; fn < 22; fn++) {
            int col = fn * 16 + r16; if (col > 342) col = 342;
            #pragma unroll
            for (int r = 0; r < 4; r++) {
                int n = row0 + quad * 4 + r; if (n > 342) n = 342;
                sacc[fn][r] = bf2f(biash[(size_t)n * 343 + col]);
            }
        }
        #pragma unroll
        for (int fn = 0; fn < 22; fn++) {
            s16x8 kb = *(const s16x8*)&Ks[(fn * 16 + r16) * 40 + quad * 8];
            sacc[fn] = __builtin_amdgcn_mfma_f32_16x16x32_bf16(qa, kb, sacc[fn], 0, 0, 0);
        }

        // ---- softmax: p = (same region) ? exp2(s) : 0 (no max-sub) ----
        float rowsum[4] = {0.f, 0.f, 0.f, 0.f};
        #pragma unroll
        for (int fn = 0; fn < 22; fn++) {
            const int col = fn * 16 + r16;
            #pragma unroll
            for (int r = 0; r < 4; r++) {
                float p = 0.0f;
                if (col < 343 && cntc[fn] == cr[r])
                    p = exp2f(fminf(sacc[fn][r], 42.0f));
                sacc[fn][r] = p;
                rowsum[r] += p;
            }
        }
        #pragma unroll
        for (int r = 0; r < 4; r++) {
            float v = rowsum[r];
            #pragma unroll
            for (int off = 1; off < 16; off <<= 1) v += __shfl_xor(v, off, 64);
            rowsum[r] = v;
        }

        // ---- PV in 32-col chunks: packed C->LDS->A round-trip + MFMA ----
        u16* pw = &Pb[wv][0];
        u32* pw32 = (u32*)pw;
        f32x4 oacc0 = (f32x4){0.f, 0.f, 0.f, 0.f};
        f32x4 oacc1 = (f32x4){0.f, 0.f, 0.f, 0.f};
        #pragma unroll
        for (int c = 0; c < 11; c++) {
            // WAR fence: prior chunk's reads complete before overwrite
            asm volatile("s_waitcnt lgkmcnt(0)" ::: "memory");
            #pragma unroll
            for (int r = 0; r < 4; r++)
                pw32[(quad * 4 + r) * 20 + r16] = f2bf_pk(sacc[2 * c][r], sacc[2 * c + 1][r]);
            // RAW fence: writes committed before reads issue
            asm volatile("s_waitcnt lgkmcnt(0)" ::: "memory");
            s16x8 pa = *(const s16x8*)&pw[r16 * 40 + quad * 8];
            s16x8 vb0 = *(const s16x8*)&Vt[r16 * 360 + c * 32 + quad * 8];
            s16x8 vb1 = *(const s16x8*)&Vt[(16 + r16) * 360 + c * 32 + quad * 8];
            oacc0 = __builtin_amdgcn_mfma_f32_16x16x32_bf16(pa, vb0, oacc0, 0, 0, 0);
            oacc1 = __builtin_amdgcn_mfma_f32_16x16x32_bf16(pa, vb1, oacc1, 0, 0, 0);
        }

        // ---- epilogue: fold 1/rowsum, store bf16 ----
        #pragma unroll
        for (int r = 0; r < 4; r++) {
            const int n = row0 + quad * 4 + r;
            if (n < 343) {
                const float rs = rowsum[r];
                const float inv = rs > 0.0f ? 1.0f / rs : 0.0f;
                size_t o = ((size_t)win * 343 + n) * C_DIM + hh * 32;
                out[o + r16] = f2bf(oacc0[r] * inv);
                out[o + 16 + r16] = f2bf(oacc1[r] * inv);
            }
        }
    }
}

// ---------------------------------------------------------------------------
extern "C" void kernel_launch(void* const* d_in, const int* in_sizes, int n_in,
                              void* d_out, int out_size, void* d_ws, size_t ws_size,
                              hipStream_t stream)
{
    const float* x      = (const float*)d_in[0];
    const float* g1     = (const float*)d_in[2];
    const float* b1     = (const float*)d_in[3];
    const float* qkv_w  = (const float*)d_in[4];
    const float* qkv_b  = (const float*)d_in[5];
    const float* rpb    = (const float*)d_in[6];
    const float* proj_w = (const float*)d_in[7];
    const float* proj_b = (const float*)d_in[8];
    const float* g2     = (const float*)d_in[9];
    const float* b2     = (const float*)d_in[10];
    const float* fc1_w  = (const float*)d_in[11];
    const float* fc1_b  = (const float*)d_in[12];
    const float* fc2_w  = (const float*)d_in[13];
    const float* fc2_b  = (const float*)d_in[14];

    // workspace layout (bytes); bias6 overlays xw (dead after QKV gemm)
    char* ws = (char*)d_ws;
    u16* xw        = (u16*)(ws + 0);                 // 16,861,184 B
    u16* bias6     = (u16*)(ws + 0);                 //  1,411,788 B (after QKV gemm)
    u16* qkv       = (u16*)(ws + 16861184);          // 50,583,552 B
    u16* a1        = (u16*)(ws + 0);                 // 67,444,736 B (reuse xw+qkv)
    u16* attn_out  = (u16*)(ws + 67444736);          // 16,861,184 B
    u16* h2        = attn_out;                       // reuse (attn_out dead by LN2)
    float* x2      = (float*)(ws + 84305920);        // 33,722,368 B
    u16* wbf       = (u16*)(ws + 118028288);         //    884,736 B  (~113 MB total)
    u16* qkv_wb = wbf;
    u16* proj_wb = wbf + 110592;
    u16* fc1_wb = wbf + 147456;
    u16* fc2_wb = wbf + 294912;

    cvt_k<<<dim3(1728), 256, 0, stream>>>(qkv_w, proj_w, fc1_w, fc2_w, wbf);
    ln_k<0><<<dim3(10976), 256, 0, stream>>>(x, g1, b1, xw);
    gemm_k<192, 0><<<dim3(9, 343), 256, 0, stream>>>(xw, qkv_wb, qkv_b, qkv, nullptr, 576);
    bias6_k<<<dim3(2, 343, 6), 256, 0, stream>>>(rpb, bias6);
    attn_k<<<dim3(6, 128), 512, 0, stream>>>(qkv, bias6, attn_out);
    gemm_k<192, 3><<<dim3(3, 343), 256, 0, stream>>>(attn_out, proj_wb, proj_b, x2, x, 192);
    ln_k<1><<<dim3(10976), 256, 0, stream>>>(x2, g2, b2, h2);
    gemm_k<192, 1><<<dim3(12, 343), 256, 0, stream>>>(h2, fc1_wb, fc1_b, a1, nullptr, 768);
    gemm_k<768, 2><<<dim3(3, 343), 256, 0, stream>>>(a1, fc2_wb, fc2_b, d_out, x2, 192);
}

// Round 8
// 369.465 us; speedup vs baseline: 1.2712x; 1.2712x over previous
//
#include <hip/hip_runtime.h>
#include <hip/hip_bf16.h>

typedef unsigned short u16;
typedef unsigned int u32;
typedef __attribute__((ext_vector_type(8))) short s16x8;
typedef __attribute__((ext_vector_type(4))) float f32x4;

__device__ __forceinline__ float bf2f(u16 v) {
    union { u32 u; float f; } x; x.u = ((u32)v) << 16; return x.f;
}
__device__ __forceinline__ u16 f2bf(float f) {
    union { float f; u32 u; } x; x.f = f;
    u32 r = x.u + 0x7fffu + ((x.u >> 16) & 1u);
    return (u16)(r >> 16);
}
// pack two f32 -> bf16x2 (low = a, high = b)
__device__ __forceinline__ u32 f2bf_pk(float a, float b) {
    __hip_bfloat162 hb = __float22bfloat162_rn(make_float2(a, b));
    union { __hip_bfloat162 h; u32 u; } c; c.h = hb; return c.u;
}
// async global->LDS, 16B per lane. LDS dest must be wave-uniform base + lane*16
__device__ __forceinline__ void gl2lds(const u16* g, u16* l) {
    __builtin_amdgcn_global_load_lds(
        (const __attribute__((address_space(1))) unsigned int*)g,
        (__attribute__((address_space(3))) unsigned int*)l, 16, 0, 0);
}

#define L_TOK 21952      // 28^3
#define C_DIM 192
#define LOG2E 1.4426950408889634f
#define Q2SCALE 0.2550565444463649f   // (1/sqrt(32)) * log2(e)

// ---------------------------------------------------------------------------
// Convert the 4 weight matrices f32 -> bf16 (contiguous dst buffer).
// ---------------------------------------------------------------------------
__global__ __launch_bounds__(256) void cvt_k(const float* __restrict__ s0, // 110592 qkv_w
                                             const float* __restrict__ s1, // 36864  proj_w
                                             const float* __restrict__ s2, // 147456 fc1_w
                                             const float* __restrict__ s3, // 147456 fc2_w
                                             u16* __restrict__ dst)
{
    int i = blockIdx.x * 256 + threadIdx.x;   // grid covers 442368
    float v;
    if (i < 110592) v = s0[i];
    else if (i < 147456) v = s1[i - 110592];
    else if (i < 294912) v = s2[i - 147456];
    else v = s3[i - 294912];
    dst[i] = f2bf(v);
}

// ---------------------------------------------------------------------------
// Precompute rel-pos bias per head, premultiplied by log2(e):
// bias6[hh][n][m] (bf16), 6*343*343 = 1.4 MB -> L2/L3 resident.
// ---------------------------------------------------------------------------
__global__ __launch_bounds__(256) void bias6_k(const float* __restrict__ rpb,
                                               u16* __restrict__ bias6)
{
    const int m = blockIdx.x * 256 + threadIdx.x;
    if (m >= 343) return;
    const int n = blockIdx.y, hh = blockIdx.z;
    int hq = n / 49, r1 = n - hq * 49, wq = r1 / 7, tq = r1 - wq * 7;
    int hm = m / 49, r2 = m - hm * 49, wm = r2 / 7, tm = r2 - wm * 7;
    int idx = ((hq - hm + 6) * 13 + (wq - wm + 6)) * 13 + (tq - tm + 6);
    bias6[((size_t)hh * 343 + n) * 343 + m] = f2bf(rpb[idx * 6 + hh] * LOG2E);
}

// ---------------------------------------------------------------------------
// LayerNorm: f32 in, bf16 out. MODE 0: LN + cyclic shift(-3) + window
// partition scatter -> xw (Bn*343, 192).  MODE 1: LN, same-row out.
// ---------------------------------------------------------------------------
template<int MODE>
__global__ __launch_bounds__(256) void ln_k(const float* __restrict__ in,
                                            const float* __restrict__ g,
                                            const float* __restrict__ b,
                                            u16* __restrict__ out)
{
    const int lane = threadIdx.x & 63, wv = threadIdx.x >> 6;
    const int tok = blockIdx.x * 4 + wv;   // < 43904 always (10976*4)
    size_t base = (size_t)tok * C_DIM;
    float x0 = in[base + lane];
    float x1 = in[base + 64 + lane];
    float x2 = in[base + 128 + lane];
    float s = x0 + x1 + x2;
    float sq = x0 * x0 + x1 * x1 + x2 * x2;
    #pragma unroll
    for (int off = 32; off > 0; off >>= 1) {
        s += __shfl_xor(s, off, 64);
        sq += __shfl_xor(sq, off, 64);
    }
    const float mean = s * (1.0f / 192.0f);
    float var = sq * (1.0f / 192.0f) - mean * mean;
    var = fmaxf(var, 0.0f);
    const float rstd = rsqrtf(var + 1e-5f);

    size_t obase;
    if (MODE == 0) {
        int bi = tok / L_TOK;
        int l = tok - bi * L_TOK;
        int h = l / 784;
        int rm = l - h * 784;
        int w = rm / 28;
        int t = rm - w * 28;
        int hs = h + 25; if (hs >= 28) hs -= 28;
        int ws = w + 25; if (ws >= 28) ws -= 28;
        int ts = t + 25; if (ts >= 28) ts -= 28;
        int win = ((bi * 4 + hs / 7) * 4 + ws / 7) * 4 + ts / 7;
        int n = (hs % 7) * 49 + (ws % 7) * 7 + (ts % 7);
        obase = ((size_t)win * 343 + n) * C_DIM;
    } else {
        obase = base;
    }
    #pragma unroll
    for (int i = 0; i < 3; i++) {
        int c = lane + i * 64;
        float xv = (i == 0) ? x0 : (i == 1) ? x1 : x2;
        float y = (xv - mean) * rstd * g[c] + b[c];
        out[obase + c] = f2bf(y);
    }
}

// ---------------------------------------------------------------------------
// bf16 MFMA GEMM: C(M,N) = A(M,K) @ W(N,K)^T + bias(f32). 128x64 tile, BK=32.
// Staging via global_load_lds width-16 (LDS dest = 16*t bytes = wave-uniform
// base + lane*16). Grid is (N/64, 343): n0 = fast dim so blocks sharing a
// row-tile dispatch together -> A re-reads hit L2/L3.
// EPI: 0 = bias, q-cols (gcol<192) pre-scaled by scale*log2e -> bf16 (QKV)
//      1 = bias + exact GELU -> bf16 (fc1)
//      2 = bias + f32 residual -> f32 out (fc2 -> d_out)
//      3 = bias + window-reverse/unshift scatter + f32 residual -> f32 (proj)
// ---------------------------------------------------------------------------
template<int K, int EPI>
__global__ __launch_bounds__(256) void gemm_k(const u16* __restrict__ A,
                                              const u16* __restrict__ W,
                                              const float* __restrict__ bias,
                                              void* __restrict__ outp,
                                              const void* __restrict__ resp,
                                              int Ncols)
{
    __shared__ __align__(16) u16 As[128 * 32];
    __shared__ __align__(16) u16 Bs[64 * 32];
    const int t = threadIdx.x;
    const int bm = blockIdx.y;
    const int n0 = blockIdx.x * 64;
    const int lane = t & 63, wv = t >> 6;
    const int wm = (wv >> 1) * 64, wn = (wv & 1) * 32;
    const int r16 = lane & 15, quad = lane >> 4;

    f32x4 acc[4][2];
    #pragma unroll
    for (int i = 0; i < 4; i++)
        #pragma unroll
        for (int j = 0; j < 2; j++) acc[i][j] = (f32x4){0.f, 0.f, 0.f, 0.f};

    const int ar = t >> 2, ac = (t & 3) * 8;
    const size_t abase = (size_t)bm * 128 * K;

    for (int k0 = 0; k0 < K; k0 += 32) {
        gl2lds(&A[abase + (size_t)ar * K + k0 + ac], &As[8 * t]);
        gl2lds(&A[abase + (size_t)(ar + 64) * K + k0 + ac], &As[2048 + 8 * t]);
        gl2lds(&W[(size_t)(n0 + ar) * K + k0 + ac], &Bs[8 * t]);
        __syncthreads();
        s16x8 af[4], bf[2];
        #pragma unroll
        for (int fm = 0; fm < 4; fm++)
            af[fm] = *(const s16x8*)&As[(wm + fm * 16 + r16) * 32 + quad * 8];
        #pragma unroll
        for (int fn = 0; fn < 2; fn++)
            bf[fn] = *(const s16x8*)&Bs[(wn + fn * 16 + r16) * 32 + quad * 8];
        #pragma unroll
        for (int fm = 0; fm < 4; fm++)
            #pragma unroll
            for (int fn = 0; fn < 2; fn++)
                acc[fm][fn] = __builtin_amdgcn_mfma_f32_16x16x32_bf16(af[fm], bf[fn], acc[fm][fn], 0, 0, 0);
        __syncthreads();
    }

    #pragma unroll
    for (int fm = 0; fm < 4; fm++) {
        #pragma unroll
        for (int fn = 0; fn < 2; fn++) {
            #pragma unroll
            for (int r = 0; r < 4; r++) {
                const int grow = bm * 128 + wm + fm * 16 + quad * 4 + r;
                const int gcol = n0 + wn + fn * 16 + r16;
                float v = acc[fm][fn][r] + bias[gcol];
                if (EPI == 0) {
                    if (gcol < 192) v *= Q2SCALE;   // pre-scale q (incl. log2e)
                    ((u16*)outp)[(size_t)grow * Ncols + gcol] = f2bf(v);
                } else if (EPI == 1) {
                    v = 0.5f * v * (1.0f + erff(v * 0.70710678118654752f));
                    ((u16*)outp)[(size_t)grow * Ncols + gcol] = f2bf(v);
                } else if (EPI == 2) {
                    size_t o = (size_t)grow * C_DIM + gcol;
                    ((float*)outp)[o] = v + ((const float*)resp)[o];
                } else { // EPI == 3: proj scatter + residual(x f32) -> x2 f32
                    int win = grow / 343, n = grow - win * 343;
                    int bi = win >> 6, wi = win & 63;
                    int hw = wi >> 4, ww = (wi >> 2) & 3, tw = wi & 3;
                    int ph = n / 49, rem = n - ph * 49;
                    int pw = rem / 7, pt = rem - pw * 7;
                    int h = hw * 7 + ph + 3; if (h >= 28) h -= 28;
                    int w = ww * 7 + pw + 3; if (w >= 28) w -= 28;
                    int tt = tw * 7 + pt + 3; if (tt >= 28) tt -= 28;
                    int l = (h * 28 + w) * 28 + tt;
                    size_t o = ((size_t)bi * L_TOK + l) * C_DIM + gcol;
                    ((float*)outp)[o] = v + ((const float*)resp)[o];
                }
            }
        }
    }
}

// ---------------------------------------------------------------------------
// MFMA attention. Block = (head hh, window win), 4 waves (256 thr).
// __launch_bounds__(256,2): VGPR cap 256 — the live set (~120: sacc[22]x4 +
// frags) MUST NOT spill; round 7's (512,4) capped at 64 VGPRs and spilled
// accumulators to scratch (WRITE_SIZE 16->107 MB, 2.4x slower).
// q pre-scaled by scale*log2e; bias premultiplied by log2e -> p = exp2(s).
// Structural mask (no memory read): region id per axis r = 0 if wc<3 else
// (pos<4?1:2); equal-region -> attend, else p = 0.
// P round-trip: packed bf16x2 ds_write_b32; Vt columns pre-permuted so the
// packed physical order is the PV contraction order (pure index relabel):
//   phys p = 2*(l&15) + (l>>4)  within each 32-col chunk.
// LDS: Ks 352x40 + Vt 32x360 + Pb 4x16x40 + Cn 344 = 57 KB (2 blocks/CU).
// ---------------------------------------------------------------------------
__global__ __launch_bounds__(256, 2) void attn_k(const u16* __restrict__ qkv,
                                                 const u16* __restrict__ bias6,
                                                 u16* __restrict__ out)
{
    __shared__ __align__(16) u16 Ks[352 * 40];
    __shared__ __align__(16) u16 Vt[32 * 360];
    __shared__ __align__(16) u16 Pb[4][16 * 40];
    __shared__ u16 Cn[344];

    const int hh = blockIdx.x;   // head 0..5
    const int win = blockIdx.y;  // 0..127
    const int wi = win & 63;
    const int t = threadIdx.x, lane = t & 63, wv = t >> 6;
    const int r16 = lane & 15, quad = lane >> 4;
    const size_t qbase = (size_t)win * 343 * 576 + hh * 32;

    // ---- stage K rows (343 x 32), zero pad rows 343..351 ----
    for (int j = t; j < 343 * 4; j += 256) {
        int m = j >> 2, ch = j & 3;
        *(uint4*)&Ks[m * 40 + ch * 8] = *(const uint4*)&qkv[qbase + (size_t)m * 576 + 192 + ch * 8];
    }
    if (t < 36) {
        int m = 343 + (t >> 2), ch = t & 3;
        *(uint4*)&Ks[m * 40 + ch * 8] = (uint4){0u, 0u, 0u, 0u};
    }
    // ---- stage V transposed + column-permuted: Vt[d][phys(m)] ----
    for (int i = t; i < 343 * 16; i += 256) {
        int m = i >> 4, d2 = (i & 15) * 2;
        int pm = (m & ~31) + 2 * (m & 15) + ((m >> 4) & 1);
        u32 w2 = *(const u32*)&qkv[qbase + (size_t)m * 576 + 384 + d2];
        Vt[d2 * 360 + pm] = (u16)(w2 & 0xffffu);
        Vt[(d2 + 1) * 360 + pm] = (u16)(w2 >> 16);
    }
    // zero pads (logical m 343..351 at their permuted slots), all 32 d rows
    for (int i = t; i < 32 * 9; i += 256) {
        int d = i / 9, m = 343 + i % 9;
        int pm = (m & ~31) + 2 * (m & 15) + ((m >> 4) & 1);
        Vt[d * 360 + pm] = 0;
    }
    // ---- structural mask: region-count table for this window ----
    {
        const int hw = (wi >> 4) & 3, ww = (wi >> 2) & 3, tw = wi & 3;
        for (int n = t; n < 344; n += 256) {
            int nn = n > 342 ? 342 : n;
            int ph = nn / 49, rem = nn - ph * 49;
            int pw = rem / 7, pt = rem - pw * 7;
            int rh = (hw == 3) ? (ph < 4 ? 1 : 2) : 0;
            int rw = (ww == 3) ? (pw < 4 ? 1 : 2) : 0;
            int rt = (tw == 3) ? (pt < 4 ? 1 : 2) : 0;
            Cn[n] = (u16)(rh * 9 + rw * 3 + rt);
        }
    }
    __syncthreads();

    const u16* biash = bias6 + (size_t)hh * 343 * 343;

    // per-lane column region ids (cols fixed across Q-tiles)
    u16 cntc[22];
    #pragma unroll
    for (int fn = 0; fn < 22; fn++) {
        int col = fn * 16 + r16; if (col > 342) col = 342;
        cntc[fn] = Cn[col];
    }

    for (int qt = 0; qt < 6; qt++) {
        const int row0 = qt * 64 + wv * 16;          // wave's 16 rows
        // ---- Q A-fragment (row = r16, k = quad*8+j), clamped rows ----
        int qrow = row0 + r16; if (qrow > 342) qrow = 342;
        s16x8 qa = *(const s16x8*)&qkv[qbase + (size_t)qrow * 576 + quad * 8];

        // row region ids for this tile
        u16 cr[4];
        #pragma unroll
        for (int r = 0; r < 4; r++) {
            int n = row0 + quad * 4 + r; if (n > 342) n = 342;
            cr[r] = Cn[n];
        }

        // ---- S = Q K^T with bias-initialized accumulators ----
        f32x4 sacc[22];
        #pragma unroll
        for (int fn = 0; fn < 22; fn++) {
            int col = fn * 16 + r16; if (col > 342) col = 342;
            #pragma unroll
            for (int r = 0; r < 4; r++) {
                int n = row0 + quad * 4 + r; if (n > 342) n = 342;
                sacc[fn][r] = bf2f(biash[(size_t)n * 343 + col]);
            }
        }
        #pragma unroll
        for (int fn = 0; fn < 22; fn++) {
            s16x8 kb = *(const s16x8*)&Ks[(fn * 16 + r16) * 40 + quad * 8];
            sacc[fn] = __builtin_amdgcn_mfma_f32_16x16x32_bf16(qa, kb, sacc[fn], 0, 0, 0);
        }

        // ---- softmax: p = (same region) ? exp2(s) : 0 (no max-sub) ----
        float rowsum[4] = {0.f, 0.f, 0.f, 0.f};
        #pragma unroll
        for (int fn = 0; fn < 22; fn++) {
            const int col = fn * 16 + r16;
            #pragma unroll
            for (int r = 0; r < 4; r++) {
                float p = 0.0f;
                if (col < 343 && cntc[fn] == cr[r])
                    p = exp2f(fminf(sacc[fn][r], 42.0f));
                sacc[fn][r] = p;
                rowsum[r] += p;
            }
        }
        #pragma unroll
        for (int r = 0; r < 4; r++) {
            float v = rowsum[r];
            #pragma unroll
            for (int off = 1; off < 16; off <<= 1) v += __shfl_xor(v, off, 64);
            rowsum[r] = v;
        }

        // ---- PV in 32-col chunks: packed C->LDS->A round-trip + MFMA ----
        u16* pw = &Pb[wv][0];
        u32* pw32 = (u32*)pw;
        f32x4 oacc0 = (f32x4){0.f, 0.f, 0.f, 0.f};
        f32x4 oacc1 = (f32x4){0.f, 0.f, 0.f, 0.f};
        #pragma unroll
        for (int c = 0; c < 11; c++) {
            // WAR fence: prior chunk's reads complete before overwrite
            asm volatile("s_waitcnt lgkmcnt(0)" ::: "memory");
            #pragma unroll
            for (int r = 0; r < 4; r++)
                pw32[(quad * 4 + r) * 20 + r16] = f2bf_pk(sacc[2 * c][r], sacc[2 * c + 1][r]);
            // RAW fence: writes committed before reads issue
            asm volatile("s_waitcnt lgkmcnt(0)" ::: "memory");
            s16x8 pa = *(const s16x8*)&pw[r16 * 40 + quad * 8];
            s16x8 vb0 = *(const s16x8*)&Vt[r16 * 360 + c * 32 + quad * 8];
            s16x8 vb1 = *(const s16x8*)&Vt[(16 + r16) * 360 + c * 32 + quad * 8];
            oacc0 = __builtin_amdgcn_mfma_f32_16x16x32_bf16(pa, vb0, oacc0, 0, 0, 0);
            oacc1 = __builtin_amdgcn_mfma_f32_16x16x32_bf16(pa, vb1, oacc1, 0, 0, 0);
        }

        // ---- epilogue: fold 1/rowsum, store bf16 ----
        #pragma unroll
        for (int r = 0; r < 4; r++) {
            const int n = row0 + quad * 4 + r;
            if (n < 343) {
                const float rs = rowsum[r];
                const float inv = rs > 0.0f ? 1.0f / rs : 0.0f;
                size_t o = ((size_t)win * 343 + n) * C_DIM + hh * 32;
                out[o + r16] = f2bf(oacc0[r] * inv);
                out[o + 16 + r16] = f2bf(oacc1[r] * inv);
            }
        }
    }
}

// ---------------------------------------------------------------------------
extern "C" void kernel_launch(void* const* d_in, const int* in_sizes, int n_in,
                              void* d_out, int out_size, void* d_ws, size_t ws_size,
                              hipStream_t stream)
{
    const float* x      = (const float*)d_in[0];
    const float* g1     = (const float*)d_in[2];
    const float* b1     = (const float*)d_in[3];
    const float* qkv_w  = (const float*)d_in[4];
    const float* qkv_b  = (const float*)d_in[5];
    const float* rpb    = (const float*)d_in[6];
    const float* proj_w = (const float*)d_in[7];
    const float* proj_b = (const float*)d_in[8];
    const float* g2     = (const float*)d_in[9];
    const float* b2     = (const float*)d_in[10];
    const float* fc1_w  = (const float*)d_in[11];
    const float* fc1_b  = (const float*)d_in[12];
    const float* fc2_w  = (const float*)d_in[13];
    const float* fc2_b  = (const float*)d_in[14];

    // workspace layout (bytes); bias6 overlays xw (dead after QKV gemm)
    char* ws = (char*)d_ws;
    u16* xw        = (u16*)(ws + 0);                 // 16,861,184 B
    u16* bias6     = (u16*)(ws + 0);                 //  1,411,788 B (after QKV gemm)
    u16* qkv       = (u16*)(ws + 16861184);          // 50,583,552 B
    u16* a1        = (u16*)(ws + 0);                 // 67,444,736 B (reuse xw+qkv)
    u16* attn_out  = (u16*)(ws + 67444736);          // 16,861,184 B
    u16* h2        = attn_out;                       // reuse (attn_out dead by LN2)
    float* x2      = (float*)(ws + 84305920);        // 33,722,368 B
    u16* wbf       = (u16*)(ws + 118028288);         //    884,736 B  (~113 MB total)
    u16* qkv_wb = wbf;
    u16* proj_wb = wbf + 110592;
    u16* fc1_wb = wbf + 147456;
    u16* fc2_wb = wbf + 294912;

    cvt_k<<<dim3(1728), 256, 0, stream>>>(qkv_w, proj_w, fc1_w, fc2_w, wbf);
    ln_k<0><<<dim3(10976), 256, 0, stream>>>(x, g1, b1, xw);
    gemm_k<192, 0><<<dim3(9, 343), 256, 0, stream>>>(xw, qkv_wb, qkv_b, qkv, nullptr, 576);
    bias6_k<<<dim3(2, 343, 6), 256, 0, stream>>>(rpb, bias6);
    attn_k<<<dim3(6, 128), 256, 0, stream>>>(qkv, bias6, attn_out);
    gemm_k<192, 3><<<dim3(3, 343), 256, 0, stream>>>(attn_out, proj_wb, proj_b, x2, x, 192);
    ln_k<1><<<dim3(10976), 256, 0, stream>>>(x2, g2, b2, h2);
    gemm_k<192, 1><<<dim3(12, 343), 256, 0, stream>>>(h2, fc1_wb, fc1_b, a1, nullptr, 768);
    gemm_k<768, 2><<<dim3(3, 343), 256, 0, stream>>>(a1, fc2_wb, fc2_b, d_out, x2, 192);
}

// Round 9
// 367.127 us; speedup vs baseline: 1.2793x; 1.0064x over previous
//
#include <hip/hip_runtime.h>
#include <hip/hip_bf16.h>

typedef unsigned short u16;
typedef unsigned int u32;
typedef __attribute__((ext_vector_type(8))) short s16x8;
typedef __attribute__((ext_vector_type(4))) float f32x4;

__device__ __forceinline__ float bf2f(u16 v) {
    union { u32 u; float f; } x; x.u = ((u32)v) << 16; return x.f;
}
__device__ __forceinline__ u16 f2bf(float f) {
    union { float f; u32 u; } x; x.f = f;
    u32 r = x.u + 0x7fffu + ((x.u >> 16) & 1u);
    return (u16)(r >> 16);
}
// cheap pack: two f32 -> bf16x2 (low = a, high = b)
__device__ __forceinline__ u32 f2bf_pk(float a, float b) {
    return (u32)f2bf(a) | ((u32)f2bf(b) << 16);
}
// async global->LDS, 16B per lane. LDS dest must be wave-uniform base + lane*16
__device__ __forceinline__ void gl2lds(const u16* g, u16* l) {
    __builtin_amdgcn_global_load_lds(
        (const __attribute__((address_space(1))) unsigned int*)g,
        (__attribute__((address_space(3))) unsigned int*)l, 16, 0, 0);
}

#define L_TOK 21952      // 28^3
#define C_DIM 192
#define LOG2E 1.4426950408889634f
#define Q2SCALE 0.2550565444463649f   // (1/sqrt(32)) * log2(e)
#define BT_STR 352       // bias6T n-stride (padded: n0+3 <= 351)

// ---------------------------------------------------------------------------
// Convert the 4 weight matrices f32 -> bf16 (contiguous dst buffer).
// ---------------------------------------------------------------------------
__global__ __launch_bounds__(256) void cvt_k(const float* __restrict__ s0, // 110592 qkv_w
                                             const float* __restrict__ s1, // 36864  proj_w
                                             const float* __restrict__ s2, // 147456 fc1_w
                                             const float* __restrict__ s3, // 147456 fc2_w
                                             u16* __restrict__ dst)
{
    int i = blockIdx.x * 256 + threadIdx.x;   // grid covers 442368
    float v;
    if (i < 110592) v = s0[i];
    else if (i < 147456) v = s1[i - 110592];
    else if (i < 294912) v = s2[i - 147456];
    else v = s3[i - 294912];
    dst[i] = f2bf(v);
}

// ---------------------------------------------------------------------------
// Rel-pos bias per head, TRANSPOSED (key-major) and premultiplied by log2(e):
// bias6T[hh][m][n] (bf16), n-stride 352 zero-padded. 1.45 MB -> L2-resident.
// Element [hh][m][n] = rpb[idx(query=n, key=m)][hh] * log2e.
// ---------------------------------------------------------------------------
__global__ __launch_bounds__(256) void bias6_k(const float* __restrict__ rpb,
                                               u16* __restrict__ bias6T)
{
    const int n = blockIdx.x * 256 + threadIdx.x;
    if (n >= BT_STR) return;
    const int m = blockIdx.y, hh = blockIdx.z;
    u16 v = 0;
    if (n <= 342) {
        int hq = n / 49, r1 = n - hq * 49, wq = r1 / 7, tq = r1 - wq * 7;
        int hm = m / 49, r2 = m - hm * 49, wm = r2 / 7, tm = r2 - wm * 7;
        int idx = ((hq - hm + 6) * 13 + (wq - wm + 6)) * 13 + (tq - tm + 6);
        v = f2bf(rpb[idx * 6 + hh] * LOG2E);
    }
    bias6T[((size_t)hh * 343 + m) * BT_STR + n] = v;
}

// ---------------------------------------------------------------------------
// LayerNorm: f32 in, bf16 out. MODE 0: LN + cyclic shift(-3) + window
// partition scatter -> xw (Bn*343, 192).  MODE 1: LN, same-row out.
// ---------------------------------------------------------------------------
template<int MODE>
__global__ __launch_bounds__(256) void ln_k(const float* __restrict__ in,
                                            const float* __restrict__ g,
                                            const float* __restrict__ b,
                                            u16* __restrict__ out)
{
    const int lane = threadIdx.x & 63, wv = threadIdx.x >> 6;
    const int tok = blockIdx.x * 4 + wv;   // < 43904 always (10976*4)
    size_t base = (size_t)tok * C_DIM;
    float x0 = in[base + lane];
    float x1 = in[base + 64 + lane];
    float x2 = in[base + 128 + lane];
    float s = x0 + x1 + x2;
    float sq = x0 * x0 + x1 * x1 + x2 * x2;
    #pragma unroll
    for (int off = 32; off > 0; off >>= 1) {
        s += __shfl_xor(s, off, 64);
        sq += __shfl_xor(sq, off, 64);
    }
    const float mean = s * (1.0f / 192.0f);
    float var = sq * (1.0f / 192.0f) - mean * mean;
    var = fmaxf(var, 0.0f);
    const float rstd = rsqrtf(var + 1e-5f);

    size_t obase;
    if (MODE == 0) {
        int bi = tok / L_TOK;
        int l = tok - bi * L_TOK;
        int h = l / 784;
        int rm = l - h * 784;
        int w = rm / 28;
        int t = rm - w * 28;
        int hs = h + 25; if (hs >= 28) hs -= 28;
        int ws = w + 25; if (ws >= 28) ws -= 28;
        int ts = t + 25; if (ts >= 28) ts -= 28;
        int win = ((bi * 4 + hs / 7) * 4 + ws / 7) * 4 + ts / 7;
        int n = (hs % 7) * 49 + (ws % 7) * 7 + (ts % 7);
        obase = ((size_t)win * 343 + n) * C_DIM;
    } else {
        obase = base;
    }
    #pragma unroll
    for (int i = 0; i < 3; i++) {
        int c = lane + i * 64;
        float xv = (i == 0) ? x0 : (i == 1) ? x1 : x2;
        float y = (xv - mean) * rstd * g[c] + b[c];
        out[obase + c] = f2bf(y);
    }
}

// ---------------------------------------------------------------------------
// bf16 MFMA GEMM: C(M,N) = A(M,K) @ W(N,K)^T + bias(f32). 128x64 tile.
// K staged in 96-wide chunks (3 k-tiles of 32): 9 async gl2lds per thread,
// ONE barrier, then 24 MFMAs. K=192 -> 2 chunks (3 barriers total, was 12);
// K=768 -> 8 chunks. LDS 36 KB -> 4 blocks/CU.
// Grid (N/64, 343): n0 fast -> A re-reads are L2/L3 hits.
// EPI: 0 = bias, q-cols (gcol<192) pre-scaled by scale*log2e -> bf16 (QKV)
//      1 = bias + exact GELU -> bf16 (fc1)
//      2 = bias + f32 residual -> f32 out (fc2 -> d_out)
//      3 = bias + window-reverse/unshift scatter + f32 residual -> f32 (proj)
// ---------------------------------------------------------------------------
template<int K, int EPI>
__global__ __launch_bounds__(256) void gemm_k(const u16* __restrict__ A,
                                              const u16* __restrict__ W,
                                              const float* __restrict__ bias,
                                              void* __restrict__ outp,
                                              const void* __restrict__ resp,
                                              int Ncols)
{
    __shared__ __align__(16) u16 As[3 * 128 * 32];   // 24 KB
    __shared__ __align__(16) u16 Bs[3 * 64 * 32];    // 12 KB
    const int t = threadIdx.x;
    const int bm = blockIdx.y;
    const int n0 = blockIdx.x * 64;
    const int lane = t & 63, wv = t >> 6;
    const int wm = (wv >> 1) * 64, wn = (wv & 1) * 32;
    const int r16 = lane & 15, quad = lane >> 4;

    f32x4 acc[4][2];
    #pragma unroll
    for (int i = 0; i < 4; i++)
        #pragma unroll
        for (int j = 0; j < 2; j++) acc[i][j] = (f32x4){0.f, 0.f, 0.f, 0.f};

    const int ar = t >> 2, ac = (t & 3) * 8;
    const size_t abase = (size_t)bm * 128 * K;

    for (int kc = 0; kc < K; kc += 96) {
        if (kc) __syncthreads();   // WAR: prior chunk's ds_reads done
        #pragma unroll
        for (int kt = 0; kt < 3; kt++) {
            const int k0 = kc + kt * 32;
            gl2lds(&A[abase + (size_t)ar * K + k0 + ac], &As[kt * 4096 + 8 * t]);
            gl2lds(&A[abase + (size_t)(ar + 64) * K + k0 + ac], &As[kt * 4096 + 2048 + 8 * t]);
            gl2lds(&W[(size_t)(n0 + ar) * K + k0 + ac], &Bs[kt * 2048 + 8 * t]);
        }
        __syncthreads();           // drains the 9 async loads
        #pragma unroll
        for (int kt = 0; kt < 3; kt++) {
            s16x8 af[4], bf[2];
            #pragma unroll
            for (int fm = 0; fm < 4; fm++)
                af[fm] = *(const s16x8*)&As[kt * 4096 + (wm + fm * 16 + r16) * 32 + quad * 8];
            #pragma unroll
            for (int fn = 0; fn < 2; fn++)
                bf[fn] = *(const s16x8*)&Bs[kt * 2048 + (wn + fn * 16 + r16) * 32 + quad * 8];
            #pragma unroll
            for (int fm = 0; fm < 4; fm++)
                #pragma unroll
                for (int fn = 0; fn < 2; fn++)
                    acc[fm][fn] = __builtin_amdgcn_mfma_f32_16x16x32_bf16(af[fm], bf[fn], acc[fm][fn], 0, 0, 0);
        }
    }

    #pragma unroll
    for (int fm = 0; fm < 4; fm++) {
        #pragma unroll
        for (int fn = 0; fn < 2; fn++) {
            #pragma unroll
            for (int r = 0; r < 4; r++) {
                const int grow = bm * 128 + wm + fm * 16 + quad * 4 + r;
                const int gcol = n0 + wn + fn * 16 + r16;
                float v = acc[fm][fn][r] + bias[gcol];
                if (EPI == 0) {
                    if (gcol < 192) v *= Q2SCALE;   // pre-scale q (incl. log2e)
                    ((u16*)outp)[(size_t)grow * Ncols + gcol] = f2bf(v);
                } else if (EPI == 1) {
                    v = 0.5f * v * (1.0f + erff(v * 0.70710678118654752f));
                    ((u16*)outp)[(size_t)grow * Ncols + gcol] = f2bf(v);
                } else if (EPI == 2) {
                    size_t o = (size_t)grow * C_DIM + gcol;
                    ((float*)outp)[o] = v + ((const float*)resp)[o];
                } else { // EPI == 3: proj scatter + residual(x f32) -> x2 f32
                    int win = grow / 343, n = grow - win * 343;
                    int bi = win >> 6, wi = win & 63;
                    int hw = wi >> 4, ww = (wi >> 2) & 3, tw = wi & 3;
                    int ph = n / 49, rem = n - ph * 49;
                    int pw = rem / 7, pt = rem - pw * 7;
                    int h = hw * 7 + ph + 3; if (h >= 28) h -= 28;
                    int w = ww * 7 + pw + 3; if (w >= 28) w -= 28;
                    int tt = tw * 7 + pt + 3; if (tt >= 28) tt -= 28;
                    int l = (h * 28 + w) * 28 + tt;
                    size_t o = ((size_t)bi * L_TOK + l) * C_DIM + gcol;
                    ((float*)outp)[o] = v + ((const float*)resp)[o];
                }
            }
        }
    }
}

// ---------------------------------------------------------------------------
// MFMA attention. Block = (head hh, window win), 4 waves (256 thr).
// __launch_bounds__(256,2): VGPR cap 256 (r7 lesson: (512,4) -> 64-VGPR cap
// spilled the 88-VGPR sacc to scratch, 2.4x slower).
// Bias init via TRANSPOSED bias6T: one dwordx2 per fn loads 4 consecutive
// query rows (was 88 scalar u16 loads/lane/tile -> now 22 dwordx2).
// q pre-scaled by scale*log2e; bias premul by log2e -> p = exp2(s).
// Structural mask (no memory read). P round-trip: packed bf16x2 ds_write_b32
// with Vt columns pre-permuted to match pack order.
// LDS: Ks 352x40 + Vt 32x360 + Pb 4x16x40 + Cn 344 = 57 KB (2 blocks/CU).
// ---------------------------------------------------------------------------
__global__ __launch_bounds__(256, 2) void attn_k(const u16* __restrict__ qkv,
                                                 const u16* __restrict__ bias6T,
                                                 u16* __restrict__ out)
{
    __shared__ __align__(16) u16 Ks[352 * 40];
    __shared__ __align__(16) u16 Vt[32 * 360];
    __shared__ __align__(16) u16 Pb[4][16 * 40];
    __shared__ u16 Cn[344];

    const int hh = blockIdx.x;   // head 0..5
    const int win = blockIdx.y;  // 0..127
    const int wi = win & 63;
    const int t = threadIdx.x, lane = t & 63, wv = t >> 6;
    const int r16 = lane & 15, quad = lane >> 4;
    const size_t qbase = (size_t)win * 343 * 576 + hh * 32;

    // ---- stage K rows (343 x 32), zero pad rows 343..351 ----
    for (int j = t; j < 343 * 4; j += 256) {
        int m = j >> 2, ch = j & 3;
        *(uint4*)&Ks[m * 40 + ch * 8] = *(const uint4*)&qkv[qbase + (size_t)m * 576 + 192 + ch * 8];
    }
    if (t < 36) {
        int m = 343 + (t >> 2), ch = t & 3;
        *(uint4*)&Ks[m * 40 + ch * 8] = (uint4){0u, 0u, 0u, 0u};
    }
    // ---- stage V transposed + column-permuted: Vt[d][phys(m)] ----
    for (int i = t; i < 343 * 16; i += 256) {
        int m = i >> 4, d2 = (i & 15) * 2;
        int pm = (m & ~31) + 2 * (m & 15) + ((m >> 4) & 1);
        u32 w2 = *(const u32*)&qkv[qbase + (size_t)m * 576 + 384 + d2];
        Vt[d2 * 360 + pm] = (u16)(w2 & 0xffffu);
        Vt[(d2 + 1) * 360 + pm] = (u16)(w2 >> 16);
    }
    // zero pads (logical m 343..351 at their permuted slots), all 32 d rows
    for (int i = t; i < 32 * 9; i += 256) {
        int d = i / 9, m = 343 + i % 9;
        int pm = (m & ~31) + 2 * (m & 15) + ((m >> 4) & 1);
        Vt[d * 360 + pm] = 0;
    }
    // ---- structural mask: region-count table for this window ----
    {
        const int hw = (wi >> 4) & 3, ww = (wi >> 2) & 3, tw = wi & 3;
        for (int n = t; n < 344; n += 256) {
            int nn = n > 342 ? 342 : n;
            int ph = nn / 49, rem = nn - ph * 49;
            int pw = rem / 7, pt = rem - pw * 7;
            int rh = (hw == 3) ? (ph < 4 ? 1 : 2) : 0;
            int rw = (ww == 3) ? (pw < 4 ? 1 : 2) : 0;
            int rt = (tw == 3) ? (pt < 4 ? 1 : 2) : 0;
            Cn[n] = (u16)(rh * 9 + rw * 3 + rt);
        }
    }
    __syncthreads();

    const u16* biashT = bias6T + (size_t)hh * 343 * BT_STR;

    // per-lane column region ids (cols fixed across Q-tiles)
    u16 cntc[22];
    #pragma unroll
    for (int fn = 0; fn < 22; fn++) {
        int col = fn * 16 + r16; if (col > 342) col = 342;
        cntc[fn] = Cn[col];
    }

    for (int qt = 0; qt < 6; qt++) {
        const int row0 = qt * 64 + wv * 16;          // wave's 16 rows
        if (row0 > 342) continue;                    // wave-uniform early out
        // ---- Q A-fragment (row = r16, k = quad*8+j), clamped rows ----
        int qrow = row0 + r16; if (qrow > 342) qrow = 342;
        s16x8 qa = *(const s16x8*)&qkv[qbase + (size_t)qrow * 576 + quad * 8];

        // row region ids for this tile
        const int n0 = row0 + quad * 4;
        u16 cr[4];
        #pragma unroll
        for (int r = 0; r < 4; r++) {
            int n = n0 + r; if (n > 342) n = 342;
            cr[r] = Cn[n];
        }

        // ---- S = Q K^T, acc initialized from transposed bias (dwordx2) ----
        f32x4 sacc[22];
        #pragma unroll
        for (int fn = 0; fn < 22; fn++) {
            int col = fn * 16 + r16; if (col > 342) col = 342;
            uint2 bv = *(const uint2*)&biashT[(size_t)col * BT_STR + n0];
            sacc[fn][0] = bf2f((u16)(bv.x & 0xffffu));
            sacc[fn][1] = bf2f((u16)(bv.x >> 16));
            sacc[fn][2] = bf2f((u16)(bv.y & 0xffffu));
            sacc[fn][3] = bf2f((u16)(bv.y >> 16));
        }
        #pragma unroll
        for (int fn = 0; fn < 22; fn++) {
            s16x8 kb = *(const s16x8*)&Ks[(fn * 16 + r16) * 40 + quad * 8];
            sacc[fn] = __builtin_amdgcn_mfma_f32_16x16x32_bf16(qa, kb, sacc[fn], 0, 0, 0);
        }

        // ---- softmax: p = (same region) ? exp2(s) : 0 (no max-sub) ----
        float rowsum[4] = {0.f, 0.f, 0.f, 0.f};
        #pragma unroll
        for (int fn = 0; fn < 22; fn++) {
            const int col = fn * 16 + r16;
            #pragma unroll
            for (int r = 0; r < 4; r++) {
                float p = 0.0f;
                if (col < 343 && cntc[fn] == cr[r])
                    p = exp2f(fminf(sacc[fn][r], 42.0f));
                sacc[fn][r] = p;
                rowsum[r] += p;
            }
        }
        #pragma unroll
        for (int r = 0; r < 4; r++) {
            float v = rowsum[r];
            #pragma unroll
            for (int off = 1; off < 16; off <<= 1) v += __shfl_xor(v, off, 64);
            rowsum[r] = v;
        }

        // ---- PV in 32-col chunks: packed C->LDS->A round-trip + MFMA ----
        u16* pw = &Pb[wv][0];
        u32* pw32 = (u32*)pw;
        f32x4 oacc0 = (f32x4){0.f, 0.f, 0.f, 0.f};
        f32x4 oacc1 = (f32x4){0.f, 0.f, 0.f, 0.f};
        #pragma unroll
        for (int c = 0; c < 11; c++) {
            // WAR fence: prior chunk's reads complete before overwrite
            asm volatile("s_waitcnt lgkmcnt(0)" ::: "memory");
            #pragma unroll
            for (int r = 0; r < 4; r++)
                pw32[(quad * 4 + r) * 20 + r16] = f2bf_pk(sacc[2 * c][r], sacc[2 * c + 1][r]);
            // RAW fence: writes committed before reads issue
            asm volatile("s_waitcnt lgkmcnt(0)" ::: "memory");
            s16x8 pa = *(const s16x8*)&pw[r16 * 40 + quad * 8];
            s16x8 vb0 = *(const s16x8*)&Vt[r16 * 360 + c * 32 + quad * 8];
            s16x8 vb1 = *(const s16x8*)&Vt[(16 + r16) * 360 + c * 32 + quad * 8];
            oacc0 = __builtin_amdgcn_mfma_f32_16x16x32_bf16(pa, vb0, oacc0, 0, 0, 0);
            oacc1 = __builtin_amdgcn_mfma_f32_16x16x32_bf16(pa, vb1, oacc1, 0, 0, 0);
        }

        // ---- epilogue: fold 1/rowsum, store bf16 ----
        #pragma unroll
        for (int r = 0; r < 4; r++) {
            const int n = n0 + r;
            if (n < 343) {
                const float rs = rowsum[r];
                const float inv = rs > 0.0f ? 1.0f / rs : 0.0f;
                size_t o = ((size_t)win * 343 + n) * C_DIM + hh * 32;
                out[o + r16] = f2bf(oacc0[r] * inv);
                out[o + 16 + r16] = f2bf(oacc1[r] * inv);
            }
        }
    }
}

// ---------------------------------------------------------------------------
extern "C" void kernel_launch(void* const* d_in, const int* in_sizes, int n_in,
                              void* d_out, int out_size, void* d_ws, size_t ws_size,
                              hipStream_t stream)
{
    const float* x      = (const float*)d_in[0];
    const float* g1     = (const float*)d_in[2];
    const float* b1     = (const float*)d_in[3];
    const float* qkv_w  = (const float*)d_in[4];
    const float* qkv_b  = (const float*)d_in[5];
    const float* rpb    = (const float*)d_in[6];
    const float* proj_w = (const float*)d_in[7];
    const float* proj_b = (const float*)d_in[8];
    const float* g2     = (const float*)d_in[9];
    const float* b2     = (const float*)d_in[10];
    const float* fc1_w  = (const float*)d_in[11];
    const float* fc1_b  = (const float*)d_in[12];
    const float* fc2_w  = (const float*)d_in[13];
    const float* fc2_b  = (const float*)d_in[14];

    // workspace layout (bytes); bias6T overlays xw (dead after QKV gemm)
    char* ws = (char*)d_ws;
    u16* xw        = (u16*)(ws + 0);                 // 16,861,184 B
    u16* bias6T    = (u16*)(ws + 0);                 //  1,449,216 B (after QKV gemm)
    u16* qkv       = (u16*)(ws + 16861184);          // 50,583,552 B
    u16* a1        = (u16*)(ws + 0);                 // 67,444,736 B (reuse xw+qkv)
    u16* attn_out  = (u16*)(ws + 67444736);          // 16,861,184 B
    u16* h2        = attn_out;                       // reuse (attn_out dead by LN2)
    float* x2      = (float*)(ws + 84305920);        // 33,722,368 B
    u16* wbf       = (u16*)(ws + 118028288);         //    884,736 B  (~113 MB total)
    u16* qkv_wb = wbf;
    u16* proj_wb = wbf + 110592;
    u16* fc1_wb = wbf + 147456;
    u16* fc2_wb = wbf + 294912;

    cvt_k<<<dim3(1728), 256, 0, stream>>>(qkv_w, proj_w, fc1_w, fc2_w, wbf);
    ln_k<0><<<dim3(10976), 256, 0, stream>>>(x, g1, b1, xw);
    gemm_k<192, 0><<<dim3(9, 343), 256, 0, stream>>>(xw, qkv_wb, qkv_b, qkv, nullptr, 576);
    bias6_k<<<dim3(2, 343, 6), 256, 0, stream>>>(rpb, bias6T);
    attn_k<<<dim3(6, 128), 256, 0, stream>>>(qkv, bias6T, attn_out);
    gemm_k<192, 3><<<dim3(3, 343), 256, 0, stream>>>(attn_out, proj_wb, proj_b, x2, x, 192);
    ln_k<1><<<dim3(10976), 256, 0, stream>>>(x2, g2, b2, h2);
    gemm_k<192, 1><<<dim3(12, 343), 256, 0, stream>>>(h2, fc1_wb, fc1_b, a1, nullptr, 768);
    gemm_k<768, 2><<<dim3(3, 343), 256, 0, stream>>>(a1, fc2_wb, fc2_b, d_out, x2, 192);
}